// Round 7
// baseline (213.920 us; speedup 1.0000x reference)
//
#include <hip/hip_runtime.h>

typedef float f32x4 __attribute__((ext_vector_type(4)));
typedef float f32x2 __attribute__((ext_vector_type(2)));

#define NSEAS 3
#define NRES  2
#define NCOMP 5
#define KNB   8
#define TWO_PI_F 6.28318530717958647692f
#define SPB  100         // stations per block; 1000 * 100 = 100000 exactly
#define BSIG 256         // 4 waves per block

static __device__ __forceinline__ f32x2 bc2(float x) {
    f32x2 r; r.x = x; r.y = x; return r;
}

// Contiguous-wave-store variant.
// Phase 1a: lane tid<nst computes smoothed 12 coeffs for station stBeg+tid -> LDS.
// Phase 1b: lane l owns t = 16l .. 16l+15 (one wave spans a full row);
//           sin/cos basis for 16 t x 5 comps lives in registers.
// Phase 2:  wave w sweeps 25 CONSECUTIVE stations; per station the wave
//           stores the whole 4000-B row as 4 back-to-back dwordx4 per lane
//           -> each wave emits a ~100 KB contiguous ascending store run.
__global__ __launch_bounds__(BSIG) void fused_insar_kernel(
    const float* __restrict__ time_vector,
    const float* __restrict__ constant_offset,
    const float* __restrict__ linear_trend,
    const float* __restrict__ seas_amp,
    const float* __restrict__ seas_phase,
    const float* __restrict__ res_amp,
    const float* __restrict__ res_phase,
    const float* __restrict__ res_periods,
    const float* __restrict__ periods,
    const int*   __restrict__ nb_idx,
    const float* __restrict__ nb_w,
    float* __restrict__ out,
    int N, int T)
{
    __shared__ __align__(16) float sp[SPB * 12];

    const int tid   = threadIdx.x;
    const int stBeg = blockIdx.x * SPB;
    const int nst   = min(SPB, N - stBeg);   // 100 for all blocks here

    // ---------------- Phase 1a: smoothing -> LDS (one lane per station) ---
    if (tid < nst) {
        const int st = stBeg + tid;
        const float S = 0.12f, OMS = 1.0f - 0.12f;

        const int4*  ip = reinterpret_cast<const int4*>(nb_idx + st * KNB);
        const f32x4* wp = reinterpret_cast<const f32x4*>(nb_w + st * KNB);
        int4  i0 = ip[0], i1 = ip[1];
        f32x4 w0 = wp[0], w1 = wp[1];
        int   idx[KNB] = {i0.x, i0.y, i0.z, i0.w, i1.x, i1.y, i1.z, i1.w};
        float w[KNB]   = {w0.x, w0.y, w0.z, w0.w, w1.x, w1.y, w1.z, w1.w};

        float accA[NSEAS]  = {0.f, 0.f, 0.f};
        float accRe[NSEAS] = {0.f, 0.f, 0.f};
        float accIm[NSEAS] = {0.f, 0.f, 0.f};

        #pragma unroll
        for (int k = 0; k < KNB; ++k) {
            int nb = idx[k];
            #pragma unroll
            for (int i = 0; i < NSEAS; ++i) {
                float a = seas_amp[nb * NSEAS + i];
                float p = seas_phase[nb * NSEAS + i];
                float spn, cpn;
                __sincosf(p, &spn, &cpn);
                accA[i]  = fmaf(w[k], a,   accA[i]);
                accRe[i] = fmaf(w[k], cpn, accRe[i]);
                accIm[i] = fmaf(w[k], spn, accIm[i]);
            }
        }

        float outp[12];
        outp[0] = constant_offset[st];
        outp[1] = linear_trend[st];

        #pragma unroll
        for (int i = 0; i < NSEAS; ++i) {
            float smA = OMS * seas_amp[st * NSEAS + i] + S * accA[i];
            float spn, cpn;
            __sincosf(seas_phase[st * NSEAS + i], &spn, &cpn);
            float re = OMS * cpn + S * accRe[i];
            float im = OMS * spn + S * accIm[i];
            // cos(atan2(im,re)) = re/r ; sin(atan2(im,re)) = im/r
            float r   = sqrtf(re * re + im * im);
            float inv = smA / fmaxf(r, 1e-30f);
            outp[2 + 2 * i] = re * inv;
            outp[3 + 2 * i] = im * inv;
        }

        #pragma unroll
        for (int i = 0; i < NRES; ++i) {
            float a = res_amp[st * NRES + i];
            float spn, cpn;
            __sincosf(res_phase[st * NRES + i], &spn, &cpn);
            outp[2 + 2 * (NSEAS + i)] = a * cpn;
            outp[3 + 2 * (NSEAS + i)] = a * spn;
        }

        f32x4* po = reinterpret_cast<f32x4*>(sp + tid * 12);
        po[0] = f32x4{outp[0], outp[1], outp[2],  outp[3]};
        po[1] = f32x4{outp[4], outp[5], outp[6],  outp[7]};
        po[2] = f32x4{outp[8], outp[9], outp[10], outp[11]};
    }

    // ---------------- Phase 1b: 16-element time basis in registers -------
    const int lane = tid & 63;
    const int wv   = tid >> 6;           // wave 0..3
    const int e0   = lane * 16;          // first t this thread owns
    int nel = T - e0;                    // elements this thread owns
    nel = nel < 0 ? 0 : (nel > 16 ? 16 : nel);
    const int nq  = nel >> 2;            // full float4 groups (4; lane62: 2)

    float fr[NCOMP];
    fr[0] = 1.0f / periods[0];
    fr[1] = 1.0f / periods[1];
    fr[2] = 1.0f / periods[2];
    fr[3] = 1.0f / res_periods[0];
    fr[4] = 1.0f / res_periods[1];

    f32x2 tvp[8];
    f32x2 sb[NCOMP][8], cb[NCOMP][8];
    #pragma unroll
    for (int q = 0; q < 4; ++q) {
        if (q < nq) {
            f32x4 t4 = *reinterpret_cast<const f32x4*>(time_vector + e0 + 4 * q);
            tvp[2 * q].x     = t4.x; tvp[2 * q].y     = t4.y;
            tvp[2 * q + 1].x = t4.z; tvp[2 * q + 1].y = t4.w;
            #pragma unroll
            for (int c = 0; c < NCOMP; ++c) {
                float wc = TWO_PI_F * fr[c];
                float s0, c0, s1, c1, s2, c2, s3, c3;
                __sincosf(wc * t4.x, &s0, &c0);
                __sincosf(wc * t4.y, &s1, &c1);
                __sincosf(wc * t4.z, &s2, &c2);
                __sincosf(wc * t4.w, &s3, &c3);
                sb[c][2 * q].x = s0;     sb[c][2 * q].y = s1;
                sb[c][2 * q + 1].x = s2; sb[c][2 * q + 1].y = s3;
                cb[c][2 * q].x = c0;     cb[c][2 * q].y = c1;
                cb[c][2 * q + 1].x = c2; cb[c][2 * q + 1].y = c3;
            }
        }
    }

    __syncthreads();

    // ---------------- Phase 2: per-wave contiguous station sweep ---------
    const f32x4* spv = reinterpret_cast<const f32x4*>(sp);
    const int per = (nst + 3) >> 2;                 // 25
    const int sBegW = wv * per;
    const int sEndW = min(sBegW + per, nst);

    for (int s = sBegW; s < sEndW; ++s) {
        // Wave-uniform coeff broadcast from LDS.
        f32x4 P0 = spv[3 * s], P1 = spv[3 * s + 1], P2 = spv[3 * s + 2];
        float cs[NCOMP] = {P0.z, P1.x, P1.z, P2.x, P2.z};
        float cc[NCOMP] = {P0.w, P1.y, P1.w, P2.y, P2.w};
        float* orow = out + (size_t)(stBeg + s) * T + e0;

        if (nel == 16) {
            f32x2 a[8];
            f32x2 of = bc2(P0.x), tr = bc2(P0.y);
            #pragma unroll
            for (int p = 0; p < 8; ++p)
                a[p] = __builtin_elementwise_fma(tr, tvp[p], of);
            #pragma unroll
            for (int c = 0; c < NCOMP; ++c) {
                f32x2 vs = bc2(cs[c]), vc = bc2(cc[c]);
                #pragma unroll
                for (int p = 0; p < 8; ++p) {
                    a[p] = __builtin_elementwise_fma(vs, sb[c][p],
                           __builtin_elementwise_fma(vc, cb[c][p], a[p]));
                }
            }
            // 4 back-to-back dwordx4: this wave covers the full row segment.
            #pragma unroll
            for (int q = 0; q < 4; ++q) {
                f32x4 o;
                o.x = a[2 * q].x; o.y = a[2 * q].y;
                o.z = a[2 * q + 1].x; o.w = a[2 * q + 1].y;
                *reinterpret_cast<f32x4*>(orow + 4 * q) = o;
            }
        } else if (nel > 0) {
            // Partial tile (lane 62: 8 elements). Same pk math, fewer groups.
            for (int q = 0; q < nq; ++q) {
                f32x2 of = bc2(P0.x), tr = bc2(P0.y);
                f32x2 a0 = __builtin_elementwise_fma(tr, tvp[2 * q], of);
                f32x2 a1 = __builtin_elementwise_fma(tr, tvp[2 * q + 1], of);
                #pragma unroll
                for (int c = 0; c < NCOMP; ++c) {
                    f32x2 vs = bc2(cs[c]), vc = bc2(cc[c]);
                    a0 = __builtin_elementwise_fma(vs, sb[c][2 * q],
                         __builtin_elementwise_fma(vc, cb[c][2 * q], a0));
                    a1 = __builtin_elementwise_fma(vs, sb[c][2 * q + 1],
                         __builtin_elementwise_fma(vc, cb[c][2 * q + 1], a1));
                }
                f32x4 o; o.x = a0.x; o.y = a0.y; o.z = a1.x; o.w = a1.y;
                *reinterpret_cast<f32x4*>(orow + 4 * q) = o;
            }
            // Scalar tail (T % 4 != 0 only; unused for T=1000).
            for (int j = nq * 4; j < nel; ++j) {
                float tt = time_vector[e0 + j];
                float acc = fmaf(P0.y, tt, P0.x);
                #pragma unroll
                for (int c = 0; c < NCOMP; ++c) {
                    float sv, cv;
                    __sincosf(TWO_PI_F * fr[c] * tt, &sv, &cv);
                    acc = fmaf(cs[c], sv, acc);
                    acc = fmaf(cc[c], cv, acc);
                }
                orow[j] = acc;
            }
        }
    }
}

extern "C" void kernel_launch(void* const* d_in, const int* in_sizes, int n_in,
                              void* d_out, int out_size, void* d_ws, size_t ws_size,
                              hipStream_t stream) {
    const float* time_vector     = (const float*)d_in[0];
    const float* constant_offset = (const float*)d_in[1];
    const float* linear_trend    = (const float*)d_in[2];
    const float* seas_amp        = (const float*)d_in[3];
    const float* seas_phase      = (const float*)d_in[4];
    const float* res_amp         = (const float*)d_in[5];
    const float* res_phase       = (const float*)d_in[6];
    const float* res_periods     = (const float*)d_in[7];
    const float* periods         = (const float*)d_in[8];
    const int*   nb_idx          = (const int*)d_in[9];
    const float* nb_w            = (const float*)d_in[10];

    int T = in_sizes[0];
    int N = in_sizes[1];

    float* out = (float*)d_out;

    int grid = (N + SPB - 1) / SPB;   // 1000 blocks for N=100000
    fused_insar_kernel<<<grid, BSIG, 0, stream>>>(
        time_vector, constant_offset, linear_trend,
        seas_amp, seas_phase, res_amp, res_phase,
        res_periods, periods, nb_idx, nb_w,
        out, N, T);
}

// Round 8
// 108.055 us; speedup vs baseline: 1.9797x; 1.9797x over previous
//
#include <hip/hip_runtime.h>

typedef float f32x4 __attribute__((ext_vector_type(4)));
typedef float f32x2 __attribute__((ext_vector_type(2)));

#define NSEAS 3
#define NRES  2
#define NCOMP 5
#define KNB   8
#define TWO_PI_F 6.28318530717958647692f
#define SPB  100         // stations per block; grid = N/SPB = 1000
#define BSIG 256         // 4 waves per block

static __device__ __forceinline__ f32x2 bc2(float x) {
    f32x2 r; r.x = x; r.y = x; return r;
}

// Interleaved-row variant: block bx owns stations bx, bx+G, bx+2G, ...
// so all blocks concurrently write a DENSE sliding window of consecutive
// rows (fill-kernel-style global store ordering).
// Phase 1a: lane tid<spb computes smoothed coeffs for station bx+tid*G -> LDS.
// Phase 1b: thread owns t = 4*tid .. 4*tid+3; sin/cos basis in registers.
// Phase 2:  ping-pong pipelined 4-station groups, packed-f32 FMAs,
//           one f32x4 (1 KB/wave-instruction, coalesced) store per station.
__global__ __launch_bounds__(BSIG) void fused_insar_kernel(
    const float* __restrict__ time_vector,
    const float* __restrict__ constant_offset,
    const float* __restrict__ linear_trend,
    const float* __restrict__ seas_amp,
    const float* __restrict__ seas_phase,
    const float* __restrict__ res_amp,
    const float* __restrict__ res_phase,
    const float* __restrict__ res_periods,
    const float* __restrict__ periods,
    const int*   __restrict__ nb_idx,
    const float* __restrict__ nb_w,
    float* __restrict__ out,
    int N, int T)
{
    __shared__ __align__(16) float sp[SPB * 12];

    const int tid = threadIdx.x;
    const int bx  = blockIdx.x;
    const int G   = gridDim.x;
    // number of stations this block owns: count of i with bx + i*G < N
    const int nst = (N - bx + G - 1) / G;   // 100 for all blocks when N=G*SPB

    // ---------------- Phase 1a: smoothing -> LDS (one lane per station) ---
    if (tid < nst && tid < SPB) {
        const int st = bx + tid * G;
        const float S = 0.12f, OMS = 1.0f - 0.12f;

        const int4*  ip = reinterpret_cast<const int4*>(nb_idx + st * KNB);
        const f32x4* wp = reinterpret_cast<const f32x4*>(nb_w + st * KNB);
        int4  i0 = ip[0], i1 = ip[1];
        f32x4 w0 = wp[0], w1 = wp[1];
        int   idx[KNB] = {i0.x, i0.y, i0.z, i0.w, i1.x, i1.y, i1.z, i1.w};
        float w[KNB]   = {w0.x, w0.y, w0.z, w0.w, w1.x, w1.y, w1.z, w1.w};

        float accA[NSEAS]  = {0.f, 0.f, 0.f};
        float accRe[NSEAS] = {0.f, 0.f, 0.f};
        float accIm[NSEAS] = {0.f, 0.f, 0.f};

        #pragma unroll
        for (int k = 0; k < KNB; ++k) {
            int nb = idx[k];
            #pragma unroll
            for (int i = 0; i < NSEAS; ++i) {
                float a = seas_amp[nb * NSEAS + i];
                float p = seas_phase[nb * NSEAS + i];
                float spn, cpn;
                __sincosf(p, &spn, &cpn);
                accA[i]  = fmaf(w[k], a,   accA[i]);
                accRe[i] = fmaf(w[k], cpn, accRe[i]);
                accIm[i] = fmaf(w[k], spn, accIm[i]);
            }
        }

        float outp[12];
        outp[0] = constant_offset[st];
        outp[1] = linear_trend[st];

        #pragma unroll
        for (int i = 0; i < NSEAS; ++i) {
            float smA = OMS * seas_amp[st * NSEAS + i] + S * accA[i];
            float spn, cpn;
            __sincosf(seas_phase[st * NSEAS + i], &spn, &cpn);
            float re = OMS * cpn + S * accRe[i];
            float im = OMS * spn + S * accIm[i];
            // cos(atan2(im,re)) = re/r ; sin(atan2(im,re)) = im/r
            float r   = sqrtf(re * re + im * im);
            float inv = smA / fmaxf(r, 1e-30f);
            outp[2 + 2 * i] = re * inv;
            outp[3 + 2 * i] = im * inv;
        }

        #pragma unroll
        for (int i = 0; i < NRES; ++i) {
            float a = res_amp[st * NRES + i];
            float spn, cpn;
            __sincosf(res_phase[st * NRES + i], &spn, &cpn);
            outp[2 + 2 * (NSEAS + i)] = a * cpn;
            outp[3 + 2 * (NSEAS + i)] = a * spn;
        }

        f32x4* po = reinterpret_cast<f32x4*>(sp + tid * 12);
        po[0] = f32x4{outp[0], outp[1], outp[2],  outp[3]};
        po[1] = f32x4{outp[4], outp[5], outp[6],  outp[7]};
        po[2] = f32x4{outp[8], outp[9], outp[10], outp[11]};
    }

    // ---------------- Phase 1b: time basis in registers ----------------
    const int t0 = tid * 4;
    const bool active = (t0 + 3) < T;

    f32x2 tv2[2];
    f32x2 sT2[NCOMP][2], cT2[NCOMP][2];
    if (active) {
        f32x4 t4 = *reinterpret_cast<const f32x4*>(time_vector + t0);
        tv2[0].x = t4.x; tv2[0].y = t4.y;
        tv2[1].x = t4.z; tv2[1].y = t4.w;
        #pragma unroll
        for (int c = 0; c < NCOMP; ++c) {
            float f = (c < NSEAS) ? (1.0f / periods[c])
                                  : (1.0f / res_periods[c - NSEAS]);
            float wc = TWO_PI_F * f;
            float s0, c0, s1, c1, s2, c2, s3, c3;
            __sincosf(wc * t4.x, &s0, &c0);
            __sincosf(wc * t4.y, &s1, &c1);
            __sincosf(wc * t4.z, &s2, &c2);
            __sincosf(wc * t4.w, &s3, &c3);
            sT2[c][0].x = s0; sT2[c][0].y = s1;
            sT2[c][1].x = s2; sT2[c][1].y = s3;
            cT2[c][0].x = c0; cT2[c][0].y = c1;
            cT2[c][1].x = c2; cT2[c][1].y = c3;
        }
    }

    __syncthreads();

    // ---------------- Phase 2: pipelined streaming (interleaved rows) ----
    const int ngr = nst / 4;

    auto ldg = [&](int g, f32x4* C) {
        const f32x4* base = reinterpret_cast<const f32x4*>(sp) + g * 12;
        #pragma unroll
        for (int i = 0; i < 12; ++i) C[i] = base[i];
    };

    auto docg = [&](int g, const f32x4* C) {
        if (!active) return;
        #pragma unroll
        for (int u = 0; u < 4; ++u) {
            f32x4 P0 = C[3 * u], P1 = C[3 * u + 1], P2 = C[3 * u + 2];
            f32x2 of = bc2(P0.x), tr = bc2(P0.y);
            f32x2 a0 = __builtin_elementwise_fma(tr, tv2[0], of);
            f32x2 a1 = __builtin_elementwise_fma(tr, tv2[1], of);
            a0 = __builtin_elementwise_fma(bc2(P0.z), sT2[0][0], a0);
            a1 = __builtin_elementwise_fma(bc2(P0.z), sT2[0][1], a1);
            a0 = __builtin_elementwise_fma(bc2(P0.w), cT2[0][0], a0);
            a1 = __builtin_elementwise_fma(bc2(P0.w), cT2[0][1], a1);
            a0 = __builtin_elementwise_fma(bc2(P1.x), sT2[1][0], a0);
            a1 = __builtin_elementwise_fma(bc2(P1.x), sT2[1][1], a1);
            a0 = __builtin_elementwise_fma(bc2(P1.y), cT2[1][0], a0);
            a1 = __builtin_elementwise_fma(bc2(P1.y), cT2[1][1], a1);
            a0 = __builtin_elementwise_fma(bc2(P1.z), sT2[2][0], a0);
            a1 = __builtin_elementwise_fma(bc2(P1.z), sT2[2][1], a1);
            a0 = __builtin_elementwise_fma(bc2(P1.w), cT2[2][0], a0);
            a1 = __builtin_elementwise_fma(bc2(P1.w), cT2[2][1], a1);
            a0 = __builtin_elementwise_fma(bc2(P2.x), sT2[3][0], a0);
            a1 = __builtin_elementwise_fma(bc2(P2.x), sT2[3][1], a1);
            a0 = __builtin_elementwise_fma(bc2(P2.y), cT2[3][0], a0);
            a1 = __builtin_elementwise_fma(bc2(P2.y), cT2[3][1], a1);
            a0 = __builtin_elementwise_fma(bc2(P2.z), sT2[4][0], a0);
            a1 = __builtin_elementwise_fma(bc2(P2.z), sT2[4][1], a1);
            a0 = __builtin_elementwise_fma(bc2(P2.w), cT2[4][0], a0);
            a1 = __builtin_elementwise_fma(bc2(P2.w), cT2[4][1], a1);
            f32x4 o; o.x = a0.x; o.y = a0.y; o.z = a1.x; o.w = a1.y;
            // Interleaved row: all blocks write row-window [ (4g+u)*G, +G )
            size_t row = (size_t)(4 * g + u) * G + bx;
            *reinterpret_cast<f32x4*>(out + row * T + t0) = o;
        }
    };

    f32x4 A[12], B[12];
    if (ngr > 0) ldg(0, A);
    int g = 0;
    for (; g + 2 <= ngr; g += 2) {
        ldg(g + 1, B);           // issue next group's LDS reads early
        docg(g, A);              // FMAs hide the LDS latency
        if (g + 2 < ngr) ldg(g + 2, A);
        docg(g + 1, B);
    }
    if (g < ngr) docg(g, A);

    // Remainder stations (nst % 4) — generic path.
    for (int s = ngr * 4; s < nst; ++s) {
        const f32x4* pv = reinterpret_cast<const f32x4*>(sp + s * 12);
        f32x4 P0 = pv[0], P1 = pv[1], P2 = pv[2];
        float off = P0.x, trend = P0.y;
        float cs[NCOMP] = {P0.z, P1.x, P1.z, P2.x, P2.z};
        float cc[NCOMP] = {P0.w, P1.y, P1.w, P2.y, P2.w};
        size_t row = (size_t)s * G + bx;
        if (active) {
            float tvv[4] = {tv2[0].x, tv2[0].y, tv2[1].x, tv2[1].y};
            float v[4];
            #pragma unroll
            for (int j = 0; j < 4; ++j) {
                int p = j >> 1, l = j & 1;
                float acc = fmaf(trend, tvv[j], off);
                #pragma unroll
                for (int i = 0; i < NCOMP; ++i) {
                    float sv = l ? sT2[i][p].y : sT2[i][p].x;
                    float cv = l ? cT2[i][p].y : cT2[i][p].x;
                    acc = fmaf(cs[i], sv, acc);
                    acc = fmaf(cc[i], cv, acc);
                }
                v[j] = acc;
            }
            f32x4 o = {v[0], v[1], v[2], v[3]};
            *reinterpret_cast<f32x4*>(out + row * T + t0) = o;
        } else if (t0 < T) {
            for (int j = 0; j < 4 && t0 + j < T; ++j) {
                int t = t0 + j;
                float tt = time_vector[t];
                float acc = fmaf(trend, tt, off);
                for (int i = 0; i < NCOMP; ++i) {
                    float f = (i < NSEAS) ? (1.0f / periods[i])
                                          : (1.0f / res_periods[i - NSEAS]);
                    float sv, cv;
                    __sincosf(TWO_PI_F * f * tt, &sv, &cv);
                    acc = fmaf(cs[i], sv, acc);
                    acc = fmaf(cc[i], cv, acc);
                }
                out[row * T + t] = acc;
            }
        }
    }
}

extern "C" void kernel_launch(void* const* d_in, const int* in_sizes, int n_in,
                              void* d_out, int out_size, void* d_ws, size_t ws_size,
                              hipStream_t stream) {
    const float* time_vector     = (const float*)d_in[0];
    const float* constant_offset = (const float*)d_in[1];
    const float* linear_trend    = (const float*)d_in[2];
    const float* seas_amp        = (const float*)d_in[3];
    const float* seas_phase      = (const float*)d_in[4];
    const float* res_amp         = (const float*)d_in[5];
    const float* res_phase       = (const float*)d_in[6];
    const float* res_periods     = (const float*)d_in[7];
    const float* periods         = (const float*)d_in[8];
    const int*   nb_idx          = (const int*)d_in[9];
    const float* nb_w            = (const float*)d_in[10];

    int T = in_sizes[0];
    int N = in_sizes[1];

    float* out = (float*)d_out;

    int grid = (N + SPB - 1) / SPB;   // 1000 blocks for N=100000
    fused_insar_kernel<<<grid, BSIG, 0, stream>>>(
        time_vector, constant_offset, linear_trend,
        seas_amp, seas_phase, res_amp, res_phase,
        res_periods, periods, nb_idx, nb_w,
        out, N, T);
}

// Round 9
// 92.684 us; speedup vs baseline: 2.3080x; 1.1658x over previous
//
#include <hip/hip_runtime.h>

typedef float f32x4 __attribute__((ext_vector_type(4)));
typedef float f32x2 __attribute__((ext_vector_type(2)));

#define NSEAS 3
#define NRES  2
#define NCOMP 5
#define KNB   8
#define TWO_PI_F 6.28318530717958647692f
#define INV365  0.0027378508f        // 1/365.25
#define SPB  100         // stations per block; 1000 * 100 = 100000 exactly
#define BSIG 256         // 4 waves per block

static __device__ __forceinline__ f32x2 bc2(float x) {
    f32x2 r; r.x = x; r.y = x; return r;
}

// Wave-contiguous-stream variant.
// Phase 1a: lane tid<nst computes smoothed 12 coeffs for station stBeg+tid -> LDS.
// Phase 1b: each thread holds the sin/cos basis for SIXTEEN t-values:
//           t = 256q + 4*lane + j  (q=0..3, j=0..3)  -> 160 basis floats in VGPRs.
// Phase 2:  wave w sweeps 25 CONSECUTIVE stations; per station it stores the
//           whole 4000-B row as 4 back-to-back coalesced b128 instructions
//           (q=0..2 full 64 lanes = 1024 B, q=3 lanes<58 = 928 B).
//           => each wave emits a ~100 KB contiguous ascending store stream.
__global__ __launch_bounds__(BSIG) void fused_insar_kernel(
    const float* __restrict__ time_vector,
    const float* __restrict__ constant_offset,
    const float* __restrict__ linear_trend,
    const float* __restrict__ seas_amp,
    const float* __restrict__ seas_phase,
    const float* __restrict__ res_amp,
    const float* __restrict__ res_phase,
    const float* __restrict__ res_periods,
    const float* __restrict__ periods,
    const int*   __restrict__ nb_idx,
    const float* __restrict__ nb_w,
    float* __restrict__ out,
    int N, int T)
{
    __shared__ __align__(16) float sp[SPB * 12];

    const int tid   = threadIdx.x;
    const int stBeg = blockIdx.x * SPB;
    const int nst   = min(SPB, N - stBeg);   // 100 for all blocks here

    // ---------------- Phase 1a: smoothing -> LDS (one lane per station) ---
    if (tid < nst) {
        const int st = stBeg + tid;
        const float S = 0.12f, OMS = 1.0f - 0.12f;

        const int4*  ip = reinterpret_cast<const int4*>(nb_idx + st * KNB);
        const f32x4* wp = reinterpret_cast<const f32x4*>(nb_w + st * KNB);
        int4  i0 = ip[0], i1 = ip[1];
        f32x4 w0 = wp[0], w1 = wp[1];
        int   idx[KNB] = {i0.x, i0.y, i0.z, i0.w, i1.x, i1.y, i1.z, i1.w};
        float w[KNB]   = {w0.x, w0.y, w0.z, w0.w, w1.x, w1.y, w1.z, w1.w};

        float accA[NSEAS]  = {0.f, 0.f, 0.f};
        float accRe[NSEAS] = {0.f, 0.f, 0.f};
        float accIm[NSEAS] = {0.f, 0.f, 0.f};

        #pragma unroll
        for (int k = 0; k < KNB; ++k) {
            int nb = idx[k];
            #pragma unroll
            for (int i = 0; i < NSEAS; ++i) {
                float a = seas_amp[nb * NSEAS + i];
                float p = seas_phase[nb * NSEAS + i];
                float spn, cpn;
                __sincosf(p, &spn, &cpn);
                accA[i]  = fmaf(w[k], a,   accA[i]);
                accRe[i] = fmaf(w[k], cpn, accRe[i]);
                accIm[i] = fmaf(w[k], spn, accIm[i]);
            }
        }

        float outp[12];
        outp[0] = constant_offset[st];
        outp[1] = linear_trend[st];

        #pragma unroll
        for (int i = 0; i < NSEAS; ++i) {
            float smA = OMS * seas_amp[st * NSEAS + i] + S * accA[i];
            float spn, cpn;
            __sincosf(seas_phase[st * NSEAS + i], &spn, &cpn);
            float re = OMS * cpn + S * accRe[i];
            float im = OMS * spn + S * accIm[i];
            // cos(atan2(im,re)) = re/r ; sin(atan2(im,re)) = im/r
            float r   = sqrtf(re * re + im * im);
            float inv = smA / fmaxf(r, 1e-30f);
            outp[2 + 2 * i] = re * inv;
            outp[3 + 2 * i] = im * inv;
        }

        #pragma unroll
        for (int i = 0; i < NRES; ++i) {
            float a = res_amp[st * NRES + i];
            float spn, cpn;
            __sincosf(res_phase[st * NRES + i], &spn, &cpn);
            outp[2 + 2 * (NSEAS + i)] = a * cpn;
            outp[3 + 2 * (NSEAS + i)] = a * spn;
        }

        f32x4* po = reinterpret_cast<f32x4*>(sp + tid * 12);
        po[0] = f32x4{outp[0], outp[1], outp[2],  outp[3]};
        po[1] = f32x4{outp[4], outp[5], outp[6],  outp[7]};
        po[2] = f32x4{outp[8], outp[9], outp[10], outp[11]};
    }

    const int lane = tid & 63;
    const int wv   = tid >> 6;           // wave 0..3

    float fr[NCOMP];
    fr[0] = 1.0f / periods[0];
    fr[1] = 1.0f / periods[1];
    fr[2] = 1.0f / periods[2];
    fr[3] = 1.0f / res_periods[0];
    fr[4] = 1.0f / res_periods[1];

    if (T == 1000) {
        // ------------- Phase 1b: 16-element basis in registers -------------
        // element t-index: 256q + 4*lane + j  (q in 0..3, j in 0..3)
        f32x2 sb[NCOMP][4][2], cb[NCOMP][4][2];
        float baseT[4];
        #pragma unroll
        for (int q = 0; q < 4; ++q) {
            int tq = 256 * q + 4 * lane;
            baseT[q] = (float)tq;
            #pragma unroll
            for (int j = 0; j < 4; ++j) {
                int tj = tq + j; if (tj > 999) tj = 999;   // clamp (unused lanes)
                float tt = (float)tj * INV365;
                #pragma unroll
                for (int c = 0; c < NCOMP; ++c) {
                    float s, co;
                    __sincosf(TWO_PI_F * fr[c] * tt, &s, &co);
                    if (j & 1) { sb[c][q][j >> 1].y = s;  cb[c][q][j >> 1].y = co; }
                    else       { sb[c][q][j >> 1].x = s;  cb[c][q][j >> 1].x = co; }
                }
            }
        }

        __syncthreads();

        // ------------- Phase 2: per-wave contiguous station sweep ----------
        const f32x4* spv = reinterpret_cast<const f32x4*>(sp);
        const int per = (nst + 3) >> 2;
        const int s0  = min(wv * per, nst);
        const int s1  = min(s0 + per, nst);
        const bool lastq = lane < 58;    // q=3 active lanes (t <= 999)

        if (s0 < s1) {
            // Software-pipelined coeff prefetch (broadcast LDS reads).
            f32x4 Q0 = spv[3 * s0], Q1 = spv[3 * s0 + 1], Q2 = spv[3 * s0 + 2];
            for (int s = s0; s < s1; ++s) {
                f32x4 P0 = Q0, P1 = Q1, P2 = Q2;
                if (s + 1 < s1) {
                    Q0 = spv[3 * (s + 1)];
                    Q1 = spv[3 * (s + 1) + 1];
                    Q2 = spv[3 * (s + 1) + 2];
                }
                float off = P0.x;
                float trp = P0.y * INV365;      // trend per t-index
                float trp2 = trp + trp;
                float cs[NCOMP] = {P0.z, P1.x, P1.z, P2.x, P2.z};
                float cc[NCOMP] = {P0.w, P1.y, P1.w, P2.y, P2.w};
                float* orow = out + (size_t)(stBeg + s) * 1000;

                #pragma unroll
                for (int q = 0; q < 4; ++q) {
                    float b0 = fmaf(trp, baseT[q], off);
                    f32x2 a0, a1;
                    a0.x = b0;        a0.y = b0 + trp;
                    a1.x = b0 + trp2; a1.y = a1.x + trp;
                    #pragma unroll
                    for (int c = 0; c < NCOMP; ++c) {
                        f32x2 vs = bc2(cs[c]), vc = bc2(cc[c]);
                        a0 = __builtin_elementwise_fma(vs, sb[c][q][0],
                             __builtin_elementwise_fma(vc, cb[c][q][0], a0));
                        a1 = __builtin_elementwise_fma(vs, sb[c][q][1],
                             __builtin_elementwise_fma(vc, cb[c][q][1], a1));
                    }
                    if (q < 3 || lastq) {
                        f32x4 o; o.x = a0.x; o.y = a0.y; o.z = a1.x; o.w = a1.y;
                        *reinterpret_cast<f32x4*>(orow + 256 * q + 4 * lane) = o;
                    }
                }
            }
        }
    } else {
        // ------------- Generic fallback (any T) — scalar, correct ----------
        __syncthreads();
        for (int idx = tid; idx < nst * T; idx += BSIG) {
            int s = idx / T, t = idx - s * T;
            const float* p = sp + s * 12;
            float tt = time_vector[t];
            float acc = fmaf(p[1], tt, p[0]);
            #pragma unroll
            for (int c = 0; c < NCOMP; ++c) {
                float sv, cv;
                __sincosf(TWO_PI_F * fr[c] * tt, &sv, &cv);
                acc = fmaf(p[2 + 2 * c], sv, acc);
                acc = fmaf(p[3 + 2 * c], cv, acc);
            }
            out[(size_t)(stBeg + s) * T + t] = acc;
        }
    }
}

extern "C" void kernel_launch(void* const* d_in, const int* in_sizes, int n_in,
                              void* d_out, int out_size, void* d_ws, size_t ws_size,
                              hipStream_t stream) {
    const float* time_vector     = (const float*)d_in[0];
    const float* constant_offset = (const float*)d_in[1];
    const float* linear_trend    = (const float*)d_in[2];
    const float* seas_amp        = (const float*)d_in[3];
    const float* seas_phase      = (const float*)d_in[4];
    const float* res_amp         = (const float*)d_in[5];
    const float* res_phase       = (const float*)d_in[6];
    const float* res_periods     = (const float*)d_in[7];
    const float* periods         = (const float*)d_in[8];
    const int*   nb_idx          = (const int*)d_in[9];
    const float* nb_w            = (const float*)d_in[10];

    int T = in_sizes[0];
    int N = in_sizes[1];

    float* out = (float*)d_out;

    int grid = (N + SPB - 1) / SPB;   // 1000 blocks for N=100000
    fused_insar_kernel<<<grid, BSIG, 0, stream>>>(
        time_vector, constant_offset, linear_trend,
        seas_amp, seas_phase, res_amp, res_phase,
        res_periods, periods, nb_idx, nb_w,
        out, N, T);
}